// Round 1
// baseline (90.497 us; speedup 1.0000x reference)
//
#include <hip/hip_runtime.h>
#include <math.h>

// One thread per (view v, template point t) triple.
// template: (RA, 2) f32; projections: (V, 16, 2) f32.
// out: [ weights (V*RA*3) f32 | indices (V*RA*3) written as f32 ]
//
// Semantics notes (vs. float64 JAX reference):
//  - global "total / max(total)" is a positive-scalar divide -> argmin-invariant -> skipped
//  - total & bad mask are (n,m)-symmetric bitwise -> flat argmin always picks
//    sorted-order n<m -> equivalent to unordered-pair search + nearer-first orientation
//    (tie on distance -> smaller original index, matching stable argsort)
//  - all loops fully unrolled: arrays stay in registers (no scratch)

__global__ __launch_bounds__(256) void bc_kernel(
    const float* __restrict__ tmpl,   // (RA,2)
    const float* __restrict__ proj,   // (V,16,2)
    float* __restrict__ out,
    int RA, int total_n)              // total_n = V*RA
{
    int idx = blockIdx.x * blockDim.x + threadIdx.x;
    if (idx >= total_n) return;
    int v = idx / RA;
    int t = idx - v * RA;

    double tx = (double)tmpl[2 * t];
    double ty = (double)tmpl[2 * t + 1];

    const float* pv = proj + (size_t)v * 32;

    float px[16], py[16];
    double d[16];
#pragma unroll
    for (int k = 0; k < 16; k++) {
        px[k] = pv[2 * k];
        py[k] = pv[2 * k + 1];
    }
#pragma unroll
    for (int k = 0; k < 16; k++) {
        double dx = tx - (double)px[k];
        double dy = ty - (double)py[k];
        d[k] = sqrt(dx * dx + dy * dy);
    }

    // argmin distance, first occurrence on exact ties (matches stable argsort order[0])
    int ci = 0;
    double cd = d[0];
#pragma unroll
    for (int k = 1; k < 16; k++) {
        if (d[k] < cd) { cd = d[k]; ci = k; }
    }
    double cx = 0.0, cy = 0.0;
#pragma unroll
    for (int k = 0; k < 16; k++) {
        if (k == ci) { cx = (double)px[k]; cy = (double)py[k]; }
    }
    double v2x = tx - cx;
    double v2y = ty - cy;

    double best = INFINITY;
    int bi = -1, bj = -1;
    double s_di = 0.0, s_dj = 0.0;
    double s_vxi = 0.0, s_vyi = 0.0, s_vxj = 0.0, s_vyj = 0.0;

#pragma unroll
    for (int i = 0; i < 16; i++) {
#pragma unroll
        for (int j = i + 1; j < 16; j++) {
            if (i == ci || j == ci) continue;
            double vxi = (double)px[i] - cx, vyi = (double)py[i] - cy;
            double vxj = (double)px[j] - cx, vyj = (double)py[j] - cy;
            double d00i = vxi * vxi + vyi * vyi;
            double d00j = vxj * vxj + vyj * vyj;
            double d01  = vxi * vxj + vyi * vyj;
            double den  = d00i * d00j - d01 * d01;
            if (den == 0.0) continue;               // zero_mask
            double inv  = 1.0 / den;
            double d02i = vxi * v2x + vyi * v2y;
            double d02j = vxj * v2x + vyj * v2y;
            double p2 = (d02i * d00j - d01 * d02j) * inv;
            double p1 = (d00i * d02j - d01 * d02i) * inv;
            double p0 = 1.0 - p2 - p1;
            // NaN fails >= -> invalid, matching reference's isnan|out-of-range "bad"
            bool ok = (p0 >= 0.0) && (p0 <= 1.0) &&
                      (p2 >= 0.0) && (p2 <= 1.0) &&
                      (p1 >= 0.0) && (p1 <= 1.0);
            double tot = (d[i] + d[j]) + cd;
            if (ok && (tot < best)) {
                best = tot; bi = i; bj = j;
                s_di = d[i]; s_dj = d[j];
                s_vxi = vxi; s_vyi = vyi; s_vxj = vxj; s_vyj = vyj;
            }
        }
    }

    float w0 = 0.f, w1 = 0.f, w2 = 0.f;
    int i0 = 0, i1 = 0, i2 = 0;
    if (bi >= 0) {
        // orient nearer-first; exact tie -> smaller original index (bi)
        double vxn, vyn, vxm, vym;
        int n_idx, m_idx;
        if (s_dj < s_di) {
            vxn = s_vxj; vyn = s_vyj; vxm = s_vxi; vym = s_vyi;
            n_idx = bj;  m_idx = bi;
        } else {
            vxn = s_vxi; vyn = s_vyi; vxm = s_vxj; vym = s_vyj;
            n_idx = bi;  m_idx = bj;
        }
        double d00n = vxn * vxn + vyn * vyn;
        double d00m = vxm * vxm + vym * vym;
        double d01  = vxn * vxm + vyn * vym;
        double den  = d00n * d00m - d01 * d01;
        double inv  = 1.0 / den;
        double d02n = vxn * v2x + vyn * v2y;
        double d02m = vxm * v2x + vym * v2y;
        double p2 = (d02n * d00m - d01 * d02m) * inv;
        double p1 = (d00n * d02m - d01 * d02n) * inv;
        double p0 = 1.0 - p2 - p1;
        w0 = (float)p0; w1 = (float)p2; w2 = (float)p1;
        i0 = ci; i1 = n_idx; i2 = m_idx;
    }

    float* wout = out + (size_t)idx * 3;
    wout[0] = w0; wout[1] = w1; wout[2] = w2;
    float* iout = out + (size_t)total_n * 3 + (size_t)idx * 3;
    iout[0] = (float)i0; iout[1] = (float)i1; iout[2] = (float)i2;
}

extern "C" void kernel_launch(void* const* d_in, const int* in_sizes, int n_in,
                              void* d_out, int out_size, void* d_ws, size_t ws_size,
                              hipStream_t stream) {
    const float* tmpl = (const float*)d_in[0];
    const float* proj = (const float*)d_in[1];
    float* out = (float*)d_out;

    int RA = in_sizes[0] / 2;          // 40
    int V  = in_sizes[1] / 32;         // 2048 (N=16 hardcoded in kernel)
    int total_n = V * RA;              // 81920

    int block = 256;
    int grid = (total_n + block - 1) / block;
    bc_kernel<<<grid, block, 0, stream>>>(tmpl, proj, out, RA, total_n);
}

// Round 4
// 76.436 us; speedup vs baseline: 1.1840x; 1.1840x over previous
//
#include <hip/hip_runtime.h>
#include <math.h>

// One TRIPLE (view v, template point t) per LANE; 4 waves per block split the
// 120 unordered pairs (30 compile-time pairs each, via template<int W>), then
// a 3 KB LDS lexicographic-min reduce. Pair loop is division-free:
// den = d00i*d00j - d01^2 >= 0 (Gram), so  0<=p<=1  <=>  0<=num<=den.
// Epilogue recomputes the winning pair's weights with the reference's
// inv = 1/den; p = num*inv rounding.
//
// Tie-break semantics (match f64 reference, verified absmax 0.0 in round 1):
//  - argmin dist: first occurrence (stable argsort order[0])
//  - pair argmin: earliest enumeration index on exact total tie (key high bits)
//  - orientation: nearer point first; exact tie -> smaller original index

template<int W>
__device__ __forceinline__ void scan_pairs(
    const float2 (&pt)[16], const double (&d)[16],
    double cx, double cy, double v2x, double v2y, double cd, int ci,
    double& best, unsigned& bkey)
{
#pragma unroll
    for (int i = 0; i < 15; ++i) {
#pragma unroll
        for (int j = i + 1; j < 16; ++j) {
            const int p = 15 * i - (i * (i - 1)) / 2 + (j - i - 1); // 0..119
            if (p < W * 30 || p >= (W + 1) * 30) continue;  // constant-folded
            double vxi = (double)pt[i].x - cx, vyi = (double)pt[i].y - cy;
            double vxj = (double)pt[j].x - cx, vyj = (double)pt[j].y - cy;
            double d00i = vxi * vxi + vyi * vyi;
            double d00j = vxj * vxj + vyj * vyj;
            double d01  = vxi * vxj + vyi * vyj;
            double den  = d00i * d00j - d01 * d01;
            double d02i = vxi * v2x + vyi * v2y;
            double d02j = vxj * v2x + vyj * v2y;
            double num2 = d02i * d00j - d01 * d02j;
            double num1 = d00i * d02j - d01 * d02i;
            double rem  = den - num2 - num1;        // p0 * den
            bool ok = (i != ci) && (j != ci) && (den > 0.0)
                   && (num2 >= 0.0) && (num2 <= den)
                   && (num1 >= 0.0) && (num1 <= den)
                   && (rem  >= 0.0) && (rem  <= den);
            double tot = (d[i] + d[j]) + cd;
            bool swp = d[j] < d[i];                 // strict: tie keeps i first
            unsigned n = swp ? (unsigned)j : (unsigned)i;
            unsigned m = swp ? (unsigned)i : (unsigned)j;
            unsigned key = ((unsigned)p << 8) | (n << 4) | m;
            if (ok && (tot < best)) { best = tot; bkey = key; }
        }
    }
}

__global__ __launch_bounds__(256) void bc_kernel(
    const float* __restrict__ tmpl,   // (RA,2)
    const float* __restrict__ proj,   // (V,16,2)
    float* __restrict__ out,
    int RA, int total_n)
{
    __shared__ double   s_best[4][64];
    __shared__ unsigned s_key[4][64];

    int lane = threadIdx.x & 63;
    int w    = threadIdx.x >> 6;            // wave id 0..3 (uniform per wave)
    int triple = blockIdx.x * 64 + lane;
    bool active = triple < total_n;
    int tr = active ? triple : 0;
    int v = tr / RA;
    int t = tr - v * RA;

    double tx = (double)tmpl[2 * t];
    double ty = (double)tmpl[2 * t + 1];

    float2 pt[16];
    const float4* pv4 = (const float4*)(proj + (size_t)v * 32);
#pragma unroll
    for (int k = 0; k < 8; ++k) {
        float4 q = pv4[k];
        pt[2 * k]     = make_float2(q.x, q.y);
        pt[2 * k + 1] = make_float2(q.z, q.w);
    }

    double d[16];
#pragma unroll
    for (int k = 0; k < 16; ++k) {
        double dx = tx - (double)pt[k].x;
        double dy = ty - (double)pt[k].y;
        d[k] = sqrt(dx * dx + dy * dy);
    }

    // argmin distance, first occurrence on exact tie
    int ci = 0;
    double cd = d[0];
#pragma unroll
    for (int k = 1; k < 16; ++k)
        if (d[k] < cd) { cd = d[k]; ci = k; }

    float cxf = pt[0].x, cyf = pt[0].y;
#pragma unroll
    for (int k = 1; k < 16; ++k)
        if (k == ci) { cxf = pt[k].x; cyf = pt[k].y; }
    double cx = (double)cxf, cy = (double)cyf;
    double v2x = tx - cx, v2y = ty - cy;

    double best = INFINITY;
    unsigned bkey = 0xFFFFFFFFu;

    if (w == 0)      scan_pairs<0>(pt, d, cx, cy, v2x, v2y, cd, ci, best, bkey);
    else if (w == 1) scan_pairs<1>(pt, d, cx, cy, v2x, v2y, cd, ci, best, bkey);
    else if (w == 2) scan_pairs<2>(pt, d, cx, cy, v2x, v2y, cd, ci, best, bkey);
    else             scan_pairs<3>(pt, d, cx, cy, v2x, v2y, cd, ci, best, bkey);

    s_best[w][lane] = best;
    s_key[w][lane]  = bkey;
    __syncthreads();

    if (w == 0 && active) {
#pragma unroll
        for (int q = 1; q < 4; ++q) {
            double   ob = s_best[q][lane];
            unsigned okey = s_key[q][lane];
            if (ob < best || (ob == best && okey < bkey)) { best = ob; bkey = okey; }
        }

        float w0 = 0.f, w1 = 0.f, w2 = 0.f;
        int i0 = 0, i1 = 0, i2 = 0;
        if (best < INFINITY) {
            int n = (int)((bkey >> 4) & 15u);
            int m = (int)(bkey & 15u);
            const float* pvf = proj + (size_t)v * 32;
            double vxn = (double)pvf[2 * n]     - cx;
            double vyn = (double)pvf[2 * n + 1] - cy;
            double vxm = (double)pvf[2 * m]     - cx;
            double vym = (double)pvf[2 * m + 1] - cy;
            double d00n = vxn * vxn + vyn * vyn;
            double d00m = vxm * vxm + vym * vym;
            double d01  = vxn * vxm + vyn * vym;
            double den  = d00n * d00m - d01 * d01;
            double inv  = 1.0 / den;              // reference rounding path
            double d02n = vxn * v2x + vyn * v2y;
            double d02m = vxm * v2x + vym * v2y;
            double p2 = (d02n * d00m - d01 * d02m) * inv;
            double p1 = (d00n * d02m - d01 * d02n) * inv;
            double p0 = 1.0 - p2 - p1;
            w0 = (float)p0; w1 = (float)p2; w2 = (float)p1;
            i0 = ci; i1 = n; i2 = m;
        }
        float* wout = out + (size_t)tr * 3;
        wout[0] = w0; wout[1] = w1; wout[2] = w2;
        float* iout = out + (size_t)total_n * 3 + (size_t)tr * 3;
        iout[0] = (float)i0; iout[1] = (float)i1; iout[2] = (float)i2;
    }
}

extern "C" void kernel_launch(void* const* d_in, const int* in_sizes, int n_in,
                              void* d_out, int out_size, void* d_ws, size_t ws_size,
                              hipStream_t stream) {
    const float* tmpl = (const float*)d_in[0];
    const float* proj = (const float*)d_in[1];
    float* out = (float*)d_out;

    int RA = in_sizes[0] / 2;          // 40
    int V  = in_sizes[1] / 32;         // 2048 (N=16 hardcoded)
    int total_n = V * RA;              // 81920

    int block = 256;                   // 4 waves: pair-split
    int grid = (total_n + 63) / 64;    // 64 triples per block
    bc_kernel<<<grid, block, 0, stream>>>(tmpl, proj, out, RA, total_n);
}

// Round 8
// 69.120 us; speedup vs baseline: 1.3093x; 1.1058x over previous
//
#include <hip/hip_runtime.h>
#include <math.h>

// One TRIPLE (view v, template point t) per LANE; 4 waves per block split the
// 120 unordered pairs (30 compile-time pairs each via template<int W>), LDS
// lex-min reduce. Hot loop uses the 2D cross-product identity:
//   den = |a|^2|b|^2 - (a.b)^2 = (a x b)^2 = c2,  p2 = (t x b)/c,  p1 = (a x t)/c
// so validity {p0,p1,p2 in [0,1], den!=0} reduces to
//   c2 > 0  &&  u2 >= 0  &&  u1 >= 0  &&  rem >= 0
// with u2=(t x b)*c, u1=(a x t)*c, rem=c2-u2-u1. The <=c2 halves are IMPLIED
// in f64 (fl(x-y) sign-exact, gradual underflow). Pairs touching the closest
// point auto-reject: v_ci == exact 0 -> c == +-0 -> c2 == +0.
// Orientation (nearer-first; tie -> smaller original index) is applied only to
// the winner, in the epilogue, with bit-identical recomputed distances.
// Winner's weights recomputed via the reference's Gram + 1/den rounding path.

template<int W>
__device__ __forceinline__ void scan_pairs(
    const float2 (&pt)[16], const double (&d)[16],
    double cx, double cy, double v2x, double v2y, double cd,
    double& best, unsigned& bkey)
{
#pragma unroll
    for (int i = 0; i < 15; ++i) {
        double vxi = (double)pt[i].x - cx, vyi = (double)pt[i].y - cy;
        double wi  = vxi * v2y - vyi * v2x;          // a x t  (DCE'd if i unused)
#pragma unroll
        for (int j = i + 1; j < 16; ++j) {
            const int p = 15 * i - (i * (i - 1)) / 2 + (j - i - 1); // 0..119
            if (p < W * 30 || p >= (W + 1) * 30) continue;  // constant-folded
            double vxj = (double)pt[j].x - cx, vyj = (double)pt[j].y - cy;
            double wj  = vxj * v2y - vyj * v2x;      // = -(t x b), CSE'd per j
            double c   = vxi * vyj - vyi * vxj;      // a x b
            double c2  = c * c;                      // = Gram den (exact math)
            double u2  = -wj * c;                    // p2 * c2
            double u1  =  wi * c;                    // p1 * c2
            double rem = c2 - u2 - u1;               // p0 * c2
            bool ok = (c2 > 0.0) && (u2 >= 0.0) && (u1 >= 0.0) && (rem >= 0.0);
            double tot = (d[i] + d[j]) + cd;         // reference rounding order
            if (ok && (tot < best)) {
                best = tot;
                bkey = (unsigned)((p << 8) | (i << 4) | j);  // compile-time const
            }
        }
    }
}

__global__ __launch_bounds__(256) void bc_kernel(
    const float* __restrict__ tmpl,   // (RA,2)
    const float* __restrict__ proj,   // (V,16,2)
    float* __restrict__ out,
    int RA, int total_n)
{
    __shared__ double   s_best[4][64];
    __shared__ unsigned s_key[4][64];

    int lane = threadIdx.x & 63;
    int w    = threadIdx.x >> 6;            // wave id 0..3 (uniform per wave)
    int triple = blockIdx.x * 64 + lane;
    bool active = triple < total_n;
    int tr = active ? triple : 0;
    int v = tr / RA;
    int t = tr - v * RA;

    double tx = (double)tmpl[2 * t];
    double ty = (double)tmpl[2 * t + 1];

    float2 pt[16];
    const float4* pv4 = (const float4*)(proj + (size_t)v * 32);
#pragma unroll
    for (int k = 0; k < 8; ++k) {
        float4 q = pv4[k];
        pt[2 * k]     = make_float2(q.x, q.y);
        pt[2 * k + 1] = make_float2(q.z, q.w);
    }

    double d[16];
#pragma unroll
    for (int k = 0; k < 16; ++k) {
        double dx = tx - (double)pt[k].x;
        double dy = ty - (double)pt[k].y;
        d[k] = sqrt(dx * dx + dy * dy);
    }

    // argmin distance, first occurrence on exact tie (stable argsort order[0])
    int ci = 0;
    double cd = d[0];
#pragma unroll
    for (int k = 1; k < 16; ++k)
        if (d[k] < cd) { cd = d[k]; ci = k; }

    float cxf = pt[0].x, cyf = pt[0].y;
#pragma unroll
    for (int k = 1; k < 16; ++k)
        if (k == ci) { cxf = pt[k].x; cyf = pt[k].y; }
    double cx = (double)cxf, cy = (double)cyf;    // bit-copies of pt[ci]
    double v2x = tx - cx, v2y = ty - cy;

    double best = INFINITY;
    unsigned bkey = 0xFFFFFFFFu;

    if (w == 0)      scan_pairs<0>(pt, d, cx, cy, v2x, v2y, cd, best, bkey);
    else if (w == 1) scan_pairs<1>(pt, d, cx, cy, v2x, v2y, cd, best, bkey);
    else if (w == 2) scan_pairs<2>(pt, d, cx, cy, v2x, v2y, cd, best, bkey);
    else             scan_pairs<3>(pt, d, cx, cy, v2x, v2y, cd, best, bkey);

    s_best[w][lane] = best;
    s_key[w][lane]  = bkey;
    __syncthreads();

    if (w == 0 && active) {
#pragma unroll
        for (int q = 1; q < 4; ++q) {
            double   ob   = s_best[q][lane];
            unsigned okey = s_key[q][lane];
            // lexicographic (tot, enumeration-key): preserves serial first-win
            if (ob < best || (ob == best && okey < bkey)) { best = ob; bkey = okey; }
        }

        float w0 = 0.f, w1 = 0.f, w2 = 0.f;
        int i0 = 0, i1 = 0, i2 = 0;
        if (best < INFINITY) {
            int bi = (int)((bkey >> 4) & 15u);      // original order, bi < bj
            int bj = (int)(bkey & 15u);
            const float* pvf = proj + (size_t)v * 32;
            // recompute distances bit-identically to prologue d[]
            double pix = (double)pvf[2 * bi],     piy = (double)pvf[2 * bi + 1];
            double pjx = (double)pvf[2 * bj],     pjy = (double)pvf[2 * bj + 1];
            double dxi = tx - pix, dyi = ty - piy;
            double dxj = tx - pjx, dyj = ty - pjy;
            double di = sqrt(dxi * dxi + dyi * dyi);
            double dj = sqrt(dxj * dxj + dyj * dyj);
            // orient nearer-first; exact tie -> smaller original index (bi)
            bool swp = dj < di;
            double pnx = swp ? pjx : pix, pny = swp ? pjy : piy;
            double pmx = swp ? pix : pjx, pmy = swp ? piy : pjy;
            int n_idx = swp ? bj : bi,   m_idx = swp ? bi : bj;
            // reference rounding path: Gram dots + inv = 1/den
            double vxn = pnx - cx, vyn = pny - cy;
            double vxm = pmx - cx, vym = pmy - cy;
            double d00n = vxn * vxn + vyn * vyn;
            double d00m = vxm * vxm + vym * vym;
            double d01  = vxn * vxm + vyn * vym;
            double den  = d00n * d00m - d01 * d01;
            double inv  = 1.0 / den;
            double d02n = vxn * v2x + vyn * v2y;
            double d02m = vxm * v2x + vym * v2y;
            double p2 = (d02n * d00m - d01 * d02m) * inv;
            double p1 = (d00n * d02m - d01 * d02n) * inv;
            double p0 = 1.0 - p2 - p1;
            w0 = (float)p0; w1 = (float)p2; w2 = (float)p1;
            i0 = ci; i1 = n_idx; i2 = m_idx;
        }
        float* wout = out + (size_t)tr * 3;
        wout[0] = w0; wout[1] = w1; wout[2] = w2;
        float* iout = out + (size_t)total_n * 3 + (size_t)tr * 3;
        iout[0] = (float)i0; iout[1] = (float)i1; iout[2] = (float)i2;
    }
}

extern "C" void kernel_launch(void* const* d_in, const int* in_sizes, int n_in,
                              void* d_out, int out_size, void* d_ws, size_t ws_size,
                              hipStream_t stream) {
    const float* tmpl = (const float*)d_in[0];
    const float* proj = (const float*)d_in[1];
    float* out = (float*)d_out;

    int RA = in_sizes[0] / 2;          // 40
    int V  = in_sizes[1] / 32;         // 2048 (N=16 hardcoded)
    int total_n = V * RA;              // 81920

    int block = 256;                   // 4 waves: pair-split
    int grid = (total_n + 63) / 64;    // 64 triples per block
    bc_kernel<<<grid, block, 0, stream>>>(tmpl, proj, out, RA, total_n);
}